// Round 1
// baseline (111.335 us; speedup 1.0000x reference)
//
#include <hip/hip_runtime.h>
#include <hip/hip_bf16.h>
#include <cstdint>

#define DEV __device__ __forceinline__

typedef __bf16 bf16_t;
typedef __bf16 bf16x8 __attribute__((ext_vector_type(8)));
typedef __bf16 bf16x4 __attribute__((ext_vector_type(4)));
typedef float  f32x4  __attribute__((ext_vector_type(4)));

constexpr float SCALE = 0.08838834764831845f; // 1/sqrt(128)

// ---- workspace byte offsets ----
constexpr size_t OFF_WSRC = 0;                      // [128][256] bf16
constexpr size_t OFF_WDST = 65536;                  // [128][256] bf16
constexpr size_t OFF_WARR = 131072;                 // [128][256] bf16
constexpr size_t OFF_W1   = 196608;                 // [256][256] bf16
constexpr size_t OFF_W2   = 327680;                 // [128][256] bf16
constexpr size_t OFF_W3T  = 393216;                 // [128][128] bf16, w3t[o][p]=w3[p][o]
constexpr size_t OFF_FT   = 425984;                 // 3 x [64 b][64 p][128 o] bf16 (src,dst,arr)
constexpr size_t OFF_GT   = OFF_FT + 3u*1048576u;   // [64 b][64 k][128 o] bf16
constexpr size_t OFF_C    = OFF_GT + 1048576u;      // [64 b][64] f32
constexpr size_t OFF_SP   = OFF_C + 16384u;         // [64 b][64 n][256 h] f32 (src_p + b1)
constexpr size_t OFF_DP   = OFF_SP + 4194304u;      // [64 b][64 m][256 h] bf16 (dst_p)
// total = 10,928,128 bytes

DEV f32x4 mfma16(bf16x8 a, bf16x8 b, f32x4 c) {
  return __builtin_amdgcn_mfma_f32_16x16x32_bf16(a, b, c, 0, 0, 0);
}

// swizzled LDS helpers: element (row,k) lives at byte (row*ldaBytes + 2k) ^ ((row&7)<<4)
DEV bf16x8 lds_ld8(const bf16_t* base, int row, int k, int ldaBytes) {
  int off = (row * ldaBytes + k * 2) ^ ((row & 7) << 4);
  return *(const bf16x8*)((const char*)base + off);
}
DEV void lds_st8(bf16_t* base, int row, int k, int ldaBytes, bf16x8 v) {
  int off = (row * ldaBytes + k * 2) ^ ((row & 7) << 4);
  *(bf16x8*)((char*)base + off) = v;
}
DEV void lds_st1(bf16_t* base, int row, int k, int ldaBytes, bf16_t v) {
  int off = (row * ldaBytes + k * 2) ^ ((row & 7) << 4);
  *(bf16_t*)((char*)base + off) = v;
}
DEV bf16x8 g_ld8(const bf16_t* p) { return *(const bf16x8*)p; }

// ======================= K0: weight prep (fp32 -> bf16, w3 transposed) ==================
__global__ __launch_bounds__(256) void k0_prep(
    const float* __restrict__ wsrc, const float* __restrict__ wdst,
    const float* __restrict__ warr, const float* __restrict__ w1,
    const float* __restrict__ w2, const float* __restrict__ w3,
    char* __restrict__ ws)
{
  int tid = blockIdx.x * 256 + threadIdx.x;
  int stride = gridDim.x * 256;
  bf16_t* osrc = (bf16_t*)(ws + OFF_WSRC);
  bf16_t* odst = (bf16_t*)(ws + OFF_WDST);
  bf16_t* oarr = (bf16_t*)(ws + OFF_WARR);
  bf16_t* ow1  = (bf16_t*)(ws + OFF_W1);
  bf16_t* ow2  = (bf16_t*)(ws + OFF_W2);
  bf16_t* ow3t = (bf16_t*)(ws + OFF_W3T);
  for (int i = tid; i < 32768; i += stride) {
    osrc[i] = (bf16_t)wsrc[i];
    odst[i] = (bf16_t)wdst[i];
    oarr[i] = (bf16_t)warr[i];
    ow2[i]  = (bf16_t)w2[i];
  }
  for (int i = tid; i < 65536; i += stride) ow1[i] = (bf16_t)w1[i];
  for (int i = tid; i < 16384; i += stride) {
    int o = i >> 7, p = i & 127;
    ow3t[i] = (bf16_t)w3[p * 128 + o];   // w3t[o][p] = w3[p][o]
  }
}

// ======================= K1: f_X^T = (w_X @ xf + b_X)^T, per (b, X) =====================
// grid = 64*3. Output fT[p][o] bf16 ([64][128] row-major, K-contiguous for downstream A/B frags)
__global__ __launch_bounds__(256) void k1_fproj(
    const float* __restrict__ x,
    const float* __restrict__ bsrc, const float* __restrict__ bdst,
    const float* __restrict__ barr, char* __restrict__ ws)
{
  int X = blockIdx.x % 3, b = blockIdx.x / 3;
  __shared__ __attribute__((aligned(16))) bf16_t xfT[64 * 256];  // xfT[p][c], swizzled

  int t = threadIdx.x;
  const float* xb = x + (size_t)b * 16384;
  #pragma unroll
  for (int i = 0; i < 16; i++) {
    int idx4 = (i * 256 + t) * 4;           // linear in [c][p]
    int c = idx4 >> 6, p = idx4 & 63;
    f32x4 v = *(const f32x4*)(xb + idx4);
    #pragma unroll
    for (int j = 0; j < 4; j++) lds_st1(xfT, p + j, c, 512, (bf16_t)v[j]);
  }
  __syncthreads();

  const bf16_t* wb = (const bf16_t*)(ws + OFF_WSRC + (size_t)X * 65536);
  const float* bias = (X == 0) ? bsrc : ((X == 1) ? bdst : barr);
  bf16_t* fT = (bf16_t*)(ws + OFF_FT + (size_t)X * 1048576u + (size_t)b * 16384u);

  int lane = t & 63, wave = t >> 6, r16 = lane & 15, g = lane >> 4;
  f32x4 z = {0.f, 0.f, 0.f, 0.f};
  f32x4 acc[2][4];
  #pragma unroll
  for (int rf = 0; rf < 2; rf++)
    #pragma unroll
    for (int cf = 0; cf < 4; cf++) acc[rf][cf] = z;

  #pragma unroll
  for (int ks = 0; ks < 8; ks++) {
    int k = ks * 32 + g * 8;
    bf16x8 a[2], bb[4];
    #pragma unroll
    for (int rf = 0; rf < 2; rf++)
      a[rf] = g_ld8(wb + (wave * 32 + rf * 16 + r16) * 256 + k);
    #pragma unroll
    for (int cf = 0; cf < 4; cf++) bb[cf] = lds_ld8(xfT, cf * 16 + r16, k, 512);
    #pragma unroll
    for (int rf = 0; rf < 2; rf++)
      #pragma unroll
      for (int cf = 0; cf < 4; cf++) acc[rf][cf] = mfma16(a[rf], bb[cf], acc[rf][cf]);
  }
  #pragma unroll
  for (int rf = 0; rf < 2; rf++) {
    int o0 = wave * 32 + rf * 16 + g * 4;        // output row (o), j-consecutive
    f32x4 bv = *(const f32x4*)(bias + o0);
    #pragma unroll
    for (int cf = 0; cf < 4; cf++) {
      int p = cf * 16 + r16;                      // output col (position)
      bf16x4 pk;
      #pragma unroll
      for (int j = 0; j < 4; j++) pk[j] = (bf16_t)(acc[rf][cf][j] + bv[j]);
      *(bf16x4*)(fT + p * 128 + o0) = pk;         // fT[p][o0..o0+3]
    }
  }
}

// ======================= K2: move_logits, src_p(+b1), dst_p, GT, c =====================
// grid = 4*64 : task = bid>>6, b = bid&63
__global__ __launch_bounds__(256) void k2_pre(
    const float* __restrict__ b1, const float* __restrict__ b3,
    char* __restrict__ ws, float* __restrict__ out)
{
  int b = blockIdx.x & 63, task = blockIdx.x >> 6;
  int t = threadIdx.x, lane = t & 63, wave = t >> 6, r16 = lane & 15, g = lane >> 4;
  const bf16_t* fsrcT = (const bf16_t*)(ws + OFF_FT) + (size_t)b * 8192;
  const bf16_t* fdstT = (const bf16_t*)(ws + OFF_FT + 1048576u) + (size_t)b * 8192;
  const bf16_t* farrT = (const bf16_t*)(ws + OFF_FT + 2097152u) + (size_t)b * 8192;
  f32x4 z = {0.f, 0.f, 0.f, 0.f};

  if (task == 0) {
    // move[n][m] = scale * sum_d fsrcT[n][d]*fdstT[m][d]; wave covers n in [16w,16w+16)
    f32x4 acc[4];
    #pragma unroll
    for (int cf = 0; cf < 4; cf++) acc[cf] = z;
    const bf16_t* A = fsrcT + (wave * 16) * 128;
    #pragma unroll
    for (int ks = 0; ks < 4; ks++) {
      int k = ks * 32 + g * 8;
      bf16x8 a = g_ld8(A + r16 * 128 + k);
      #pragma unroll
      for (int cf = 0; cf < 4; cf++) {
        bf16x8 bb = g_ld8(fdstT + (cf * 16 + r16) * 128 + k);
        acc[cf] = mfma16(a, bb, acc[cf]);
      }
    }
    float* ob = out + (size_t)b * 4096;
    #pragma unroll
    for (int cf = 0; cf < 4; cf++)
      #pragma unroll
      for (int j = 0; j < 4; j++) {
        int n = wave * 16 + g * 4 + j, m = cf * 16 + r16;
        ob[n * 64 + m] = acc[cf][j] * SCALE;
      }
  } else if (task <= 2) {
    // src_p / dst_p: [64 n][256 h] = fT[64][128] @ w1-half; wave covers h in [64w,64w+64)
    const bf16_t* A = (task == 1) ? fsrcT : fdstT;
    const bf16_t* Bm = (const bf16_t*)(ws + OFF_W1) + (size_t)(wave * 64) * 256 + (task == 2 ? 128 : 0);
    f32x4 acc[4][4];
    #pragma unroll
    for (int rf = 0; rf < 4; rf++)
      #pragma unroll
      for (int cf = 0; cf < 4; cf++) acc[rf][cf] = z;
    #pragma unroll
    for (int ks = 0; ks < 4; ks++) {
      int k = ks * 32 + g * 8;
      bf16x8 a[4], bb[4];
      #pragma unroll
      for (int rf = 0; rf < 4; rf++) a[rf] = g_ld8(A + (rf * 16 + r16) * 128 + k);
      #pragma unroll
      for (int cf = 0; cf < 4; cf++) bb[cf] = g_ld8(Bm + (cf * 16 + r16) * 256 + k);
      #pragma unroll
      for (int rf = 0; rf < 4; rf++)
        #pragma unroll
        for (int cf = 0; cf < 4; cf++) acc[rf][cf] = mfma16(a[rf], bb[cf], acc[rf][cf]);
    }
    if (task == 1) {
      float* sp = (float*)(ws + OFF_SP) + (size_t)b * 16384;
      #pragma unroll
      for (int cf = 0; cf < 4; cf++) {
        int h = wave * 64 + cf * 16 + r16;
        float bv = b1[h];
        #pragma unroll
        for (int rf = 0; rf < 4; rf++)
          #pragma unroll
          for (int j = 0; j < 4; j++) {
            int n = rf * 16 + g * 4 + j;
            sp[n * 256 + h] = acc[rf][cf][j] + bv;
          }
      }
    } else {
      bf16_t* dpo = (bf16_t*)(ws + OFF_DP) + (size_t)b * 16384;
      #pragma unroll
      for (int cf = 0; cf < 4; cf++) {
        int h = wave * 64 + cf * 16 + r16;
        #pragma unroll
        for (int rf = 0; rf < 4; rf++)
          #pragma unroll
          for (int j = 0; j < 4; j++) {
            int m = rf * 16 + g * 4 + j;
            dpo[m * 256 + h] = (bf16_t)acc[rf][cf][j];
          }
      }
    }
  } else {
    // GT[k][o] = scale * sum_p w3t[o][p]*farrT[k][p]; wave covers o in [32w,32w+32)
    const bf16_t* A = (const bf16_t*)(ws + OFF_W3T) + (size_t)(wave * 32) * 128;
    f32x4 acc[2][4];
    #pragma unroll
    for (int rf = 0; rf < 2; rf++)
      #pragma unroll
      for (int cf = 0; cf < 4; cf++) acc[rf][cf] = z;
    #pragma unroll
    for (int ks = 0; ks < 4; ks++) {
      int k = ks * 32 + g * 8;
      bf16x8 a[2], bb[4];
      #pragma unroll
      for (int rf = 0; rf < 2; rf++) a[rf] = g_ld8(A + (rf * 16 + r16) * 128 + k);
      #pragma unroll
      for (int cf = 0; cf < 4; cf++) bb[cf] = g_ld8(farrT + (cf * 16 + r16) * 128 + k);
      #pragma unroll
      for (int rf = 0; rf < 2; rf++)
        #pragma unroll
        for (int cf = 0; cf < 4; cf++) acc[rf][cf] = mfma16(a[rf], bb[cf], acc[rf][cf]);
    }
    bf16_t* GT = (bf16_t*)(ws + OFF_GT) + (size_t)b * 8192;
    #pragma unroll
    for (int rf = 0; rf < 2; rf++) {
      int o0 = wave * 32 + rf * 16 + g * 4;
      #pragma unroll
      for (int cf = 0; cf < 4; cf++) {
        int kc = cf * 16 + r16;
        bf16x4 pk;
        #pragma unroll
        for (int j = 0; j < 4; j++) pk[j] = (bf16_t)(acc[rf][cf][j] * SCALE);
        *(bf16x4*)(GT + kc * 128 + o0) = pk;
      }
    }
    if (t < 64) {  // c[k] = scale * sum_p b3[p] * f_arr[p][k]
      float s = 0.f;
      for (int p = 0; p < 128; p++) s += b3[p] * (float)farrT[t * 128 + p];
      ((float*)(ws + OFF_C))[b * 64 + t] = s * SCALE;
    }
  }
}

// ======================= K3: per (b,n): h1 -> h2 -> arrow ==============================
// grid = 64*64, 256 threads (4 waves), LDS = 48KB
__global__ __launch_bounds__(256) void k3_main(
    const float* __restrict__ b2, const char* __restrict__ ws, float* __restrict__ out)
{
  int b = blockIdx.x >> 6, n = blockIdx.x & 63;
  __shared__ __attribute__((aligned(16))) bf16_t h1[64 * 256];  // swizzled, ldaBytes=512
  __shared__ __attribute__((aligned(16))) bf16_t h2[64 * 128];  // swizzled, ldaBytes=256
  int t = threadIdx.x, lane = t & 63, wave = t >> 6, r16 = lane & 15, g = lane >> 4;

  const bf16_t* dp = (const bf16_t*)(ws + OFF_DP) + (size_t)b * 16384;
  const float*  sp = (const float*)(ws + OFF_SP) + ((size_t)b * 64 + n) * 256;

  {  // build h1[m][k] = relu(sp[k] + dp[m][k]) once, cooperatively
    int m = t >> 2, q = t & 3;
    #pragma unroll
    for (int c8 = 0; c8 < 8; c8++) {
      int k = q * 64 + c8 * 8;
      bf16x8 dv = *(const bf16x8*)(dp + m * 256 + k);
      f32x4 s0 = *(const f32x4*)(sp + k);
      f32x4 s1 = *(const f32x4*)(sp + k + 4);
      bf16x8 hv;
      #pragma unroll
      for (int j = 0; j < 8; j++) {
        float v = (float)dv[j] + (j < 4 ? s0[j] : s1[j - 4]);
        hv[j] = (bf16_t)fmaxf(v, 0.f);
      }
      lds_st8(h1, m, k, 512, hv);
    }
  }
  __syncthreads();

  // GEMM1: h2[m][o] = relu(sum_k h1[m][k]*w2[o][k] + b2[o]); wave covers o in [32w,32w+32)
  const bf16_t* w2b = (const bf16_t*)(ws + OFF_W2);
  f32x4 z = {0.f, 0.f, 0.f, 0.f};
  f32x4 acc[4][2];
  #pragma unroll
  for (int rf = 0; rf < 4; rf++)
    #pragma unroll
    for (int cf = 0; cf < 2; cf++) acc[rf][cf] = z;
  #pragma unroll
  for (int ks = 0; ks < 8; ks++) {
    int k = ks * 32 + g * 8;
    bf16x8 a[4], bb[2];
    #pragma unroll
    for (int rf = 0; rf < 4; rf++) a[rf] = lds_ld8(h1, rf * 16 + r16, k, 512);
    #pragma unroll
    for (int cf = 0; cf < 2; cf++)
      bb[cf] = g_ld8(w2b + (wave * 32 + cf * 16 + r16) * 256 + k);
    #pragma unroll
    for (int rf = 0; rf < 4; rf++)
      #pragma unroll
      for (int cf = 0; cf < 2; cf++) acc[rf][cf] = mfma16(a[rf], bb[cf], acc[rf][cf]);
  }
  float b2v[2];
  #pragma unroll
  for (int cf = 0; cf < 2; cf++) b2v[cf] = b2[wave * 32 + cf * 16 + r16];
  #pragma unroll
  for (int rf = 0; rf < 4; rf++)
    #pragma unroll
    for (int cf = 0; cf < 2; cf++)
      #pragma unroll
      for (int j = 0; j < 4; j++) {
        int m = rf * 16 + g * 4 + j, o = wave * 32 + cf * 16 + r16;
        lds_st1(h2, m, o, 256, (bf16_t)fmaxf(acc[rf][cf][j] + b2v[cf], 0.f));
      }
  __syncthreads();

  // GEMM3': arrow[m][kc] = sum_o h2[m][o]*GT[kc][o] + c[kc]; wave covers kc in [16w,16w+16)
  const bf16_t* GTb = (const bf16_t*)(ws + OFF_GT) + (size_t)b * 8192;
  f32x4 acc2[4];
  #pragma unroll
  for (int rf = 0; rf < 4; rf++) acc2[rf] = z;
  #pragma unroll
  for (int ks = 0; ks < 4; ks++) {
    int k = ks * 32 + g * 8;
    bf16x8 bb = g_ld8(GTb + (wave * 16 + r16) * 128 + k);
    #pragma unroll
    for (int rf = 0; rf < 4; rf++) {
      bf16x8 a = lds_ld8(h2, rf * 16 + r16, k, 256);
      acc2[rf] = mfma16(a, bb, acc2[rf]);
    }
  }
  float cv = ((const float*)(ws + OFF_C))[b * 64 + wave * 16 + r16];
  float* ob = out + 262144u + ((size_t)(b * 64 + n)) * 4096u;
  #pragma unroll
  for (int rf = 0; rf < 4; rf++)
    #pragma unroll
    for (int j = 0; j < 4; j++) {
      int m = rf * 16 + g * 4 + j, kc = wave * 16 + r16;
      ob[m * 64 + kc] = acc2[rf][j] + cv;
    }
}

// ======================= launch ========================================================
extern "C" void kernel_launch(void* const* d_in, const int* in_sizes, int n_in,
                              void* d_out, int out_size, void* d_ws, size_t ws_size,
                              hipStream_t stream) {
  (void)in_sizes; (void)n_in; (void)out_size; (void)ws_size;
  const float* x    = (const float*)d_in[0];
  const float* wsrc = (const float*)d_in[1];
  const float* bsrc = (const float*)d_in[2];
  const float* wdst = (const float*)d_in[3];
  const float* bdst = (const float*)d_in[4];
  const float* warr = (const float*)d_in[5];
  const float* barr = (const float*)d_in[6];
  const float* w1   = (const float*)d_in[7];
  const float* b1   = (const float*)d_in[8];
  const float* w2   = (const float*)d_in[9];
  const float* b2   = (const float*)d_in[10];
  const float* w3   = (const float*)d_in[11];
  const float* b3   = (const float*)d_in[12];
  char* ws = (char*)d_ws;
  float* out = (float*)d_out;

  hipLaunchKernelGGL(k0_prep, dim3(64), dim3(256), 0, stream, wsrc, wdst, warr, w1, w2, w3, ws);
  hipLaunchKernelGGL(k1_fproj, dim3(192), dim3(256), 0, stream, x, bsrc, bdst, barr, ws);
  hipLaunchKernelGGL(k2_pre, dim3(256), dim3(256), 0, stream, b1, b3, ws, out);
  hipLaunchKernelGGL(k3_main, dim3(4096), dim3(256), 0, stream, b2, ws, out);
}